// Round 5
// baseline (87.076 us; speedup 1.0000x reference)
//
#include <hip/hip_runtime.h>

#define NB 2
#define NC 16
#define NH 128
#define NW 256
#define NCW 32
#define HW (NH*NW)
#define PATCH_INV (1.0f/784.0f)
#define EPS_N 1e-9f
#define HB_W 272   // hbuf row: [0..3]=0, [4..259]=prod cols 0..255, [260..271]=0

// One block per (b,y); 512 threads = 64 x-groups (4 cols) x 8 d-groups (4 disps).
// cost[b,y,x,d] = (S_LR - SL*SR/784) * invL * invR, separable 7x7 box sums.
__global__ __launch_bounds__(512) void ncc_kernel(
    const float* __restrict__ L, const float* __restrict__ R, float* __restrict__ out)
{
    __shared__ float csL[NW], cs2L[NW], csR[NW], cs2R[NW];
    __shared__ float sSL[288], sInvL[288], sSR[NW], sInvR[NW];
    __shared__ float hbuf[NCW][HB_W];

    // XCD-aware bijective swizzle (256 = 8 XCDs x 32 consecutive rows)
    const int bid = blockIdx.x;
    const int lin = (bid & 7) * 32 + (bid >> 3);
    const int b = lin >> 7;
    const int y = lin & 127;

    const int t  = threadIdx.x;
    const int dq = t >> 6;           // 0..7
    const int xg = t & 63;
    const int x0 = xg << 2;          // 4 output cols
    const int d0 = dq << 2;          // 4 disparities
    const int s  = x0 + d0;          // left window base, multiple of 4 (<=280)

    const size_t base = (size_t)b * NC * HW;

    // ---- phase A: column stats; threads 0..255 -> L col t, 256..511 -> R col t-256
    {
        const float* img = (t < 256) ? L : R;
        const int col = t & 255;
        float a = 0.f, a2 = 0.f;
        #pragma unroll
        for (int dy = -3; dy <= 3; ++dy) {
            int yy = y + dy;
            if ((unsigned)yy < NH) {
                const float* p = img + base + (size_t)yy * NW + col;
                #pragma unroll
                for (int c = 0; c < NC; ++c) {
                    float v = p[c * HW];
                    a += v; a2 += v * v;
                }
            }
        }
        if (t < 256) { csL[col] = a; cs2L[col] = a2; }
        else         { csR[col] = a; cs2R[col] = a2; }
    }
    __syncthreads();

    // ---- phase B: horizontal 7-tap -> per-pixel patch stats ----
    if (t < 288) {
        float S = 0.f, S2 = 0.f;
        #pragma unroll
        for (int dx = -3; dx <= 3; ++dx) {
            int xx = t + dx;
            if ((unsigned)xx < NW) { S += csL[xx]; S2 += cs2L[xx]; }
        }
        sSL[t]   = S;
        sInvL[t] = rsqrtf(S2 - S * S * PATCH_INV + EPS_N);
    }
    if (t >= 256) {
        const int xr = t - 256;
        float S = 0.f, S2 = 0.f;
        #pragma unroll
        for (int dx = -3; dx <= 3; ++dx) {
            int xx = xr + dx;
            if ((unsigned)xx < NW) { S += csR[xx]; S2 += cs2R[xx]; }
        }
        sSR[xr]   = S;
        sInvR[xr] = rsqrtf(S2 - S * S * PATCH_INV + EPS_N);
    }
    __syncthreads();

    // ---- phase C: channel+row product sums, 4 cols x 4 disps per thread ----
    float vp[4][4];
    #pragma unroll
    for (int i = 0; i < 4; ++i)
        #pragma unroll
        for (int j = 0; j < 4; ++j) vp[i][j] = 0.f;

    #pragma unroll
    for (int dy = -3; dy <= 3; ++dy) {
        const int yy = y + dy;
        if ((unsigned)yy < NH) {
            const float* lrow = L + base + (size_t)yy * NW;
            const float* rrow = R + base + (size_t)yy * NW;
            #pragma unroll
            for (int c = 0; c < NC; ++c) {
                const float* lc = lrow + (size_t)c * HW;
                const float* rc = rrow + (size_t)c * HW;
                float4 rv4 = *(const float4*)(rc + x0);
                float rv[4] = {rv4.x, rv4.y, rv4.z, rv4.w};
                float lw[8];
                #pragma unroll
                for (int ch = 0; ch < 2; ++ch) {
                    int col  = s + ch * 4;                       // multiple of 4
                    int colc = col < (NW - 4) ? col : (NW - 4);  // always-valid addr
                    float4 lv = *(const float4*)(lc + colc);
                    bool ok = (col < NW);                        // ext region zero
                    lw[ch*4+0] = ok ? lv.x : 0.f;
                    lw[ch*4+1] = ok ? lv.y : 0.f;
                    lw[ch*4+2] = ok ? lv.z : 0.f;
                    lw[ch*4+3] = ok ? lv.w : 0.f;
                }
                #pragma unroll
                for (int xx = 0; xx < 4; ++xx)
                    #pragma unroll
                    for (int j = 0; j < 4; ++j)
                        vp[xx][j] += lw[xx + j] * rv[xx];
            }
        }
    }
    #pragma unroll
    for (int j = 0; j < 4; ++j)
        *(float4*)&hbuf[d0 + j][4 + x0] =
            make_float4(vp[0][j], vp[1][j], vp[2][j], vp[3][j]);
    if (t < 128) {   // zero halo pads: cols 0..3 and 260..271 of each d-row
        int r = t >> 2, q = t & 3;
        int col = (q == 0) ? 0 : (260 + 4 * (q - 1));
        *(float4*)&hbuf[r][col] = make_float4(0.f, 0.f, 0.f, 0.f);
    }
    __syncthreads();

    // ---- phase D: ascending 7-tap + normalize + store ----
    float res[4][4];
    #pragma unroll
    for (int j = 0; j < 4; ++j) {
        float4 w0 = *(float4*)&hbuf[d0+j][x0];
        float4 w1 = *(float4*)&hbuf[d0+j][x0+4];
        float4 w2 = *(float4*)&hbuf[d0+j][x0+8];
        float w[12] = {w0.x,w0.y,w0.z,w0.w, w1.x,w1.y,w1.z,w1.w, w2.x,w2.y,w2.z,w2.w};
        #pragma unroll
        for (int xx = 0; xx < 4; ++xx) {
            float sum = 0.f;
            #pragma unroll
            for (int k = 1; k <= 7; ++k) sum += w[xx + k];
            float slv = sSL[s + xx + j];
            float ilv = sInvL[s + xx + j];
            float srv = sSR[x0 + xx];
            float irv = sInvR[x0 + xx];
            res[xx][j] = (sum - slv * srv * PATCH_INV) * ilv * irv;
        }
    }

    float* op = out + (((size_t)(b * NH + y) * NW) + x0) * NCW + d0;
    #pragma unroll
    for (int xx = 0; xx < 4; ++xx)
        *(float4*)(op + (size_t)xx * NCW) =
            make_float4(res[xx][0], res[xx][1], res[xx][2], res[xx][3]);
}

extern "C" void kernel_launch(void* const* d_in, const int* in_sizes, int n_in,
                              void* d_out, int out_size, void* d_ws, size_t ws_size,
                              hipStream_t stream) {
    const float* L = (const float*)d_in[0];
    const float* R = (const float*)d_in[1];
    float* out = (float*)d_out;
    ncc_kernel<<<dim3(NB * NH), dim3(512), 0, stream>>>(L, R, out);
}